// Round 1
// baseline (13963.332 us; speedup 1.0000x reference)
//
#include <hip/hip_runtime.h>
#include <math.h>

#define TPB 256
#define PIT 68   // LDS row pitch in floats: 68*4=272B, 16B-aligned rows, bank-friendly

__device__ __forceinline__ float4 ld4(const float* p) { return *(const float4*)p; }

// acc[r][c] += sum_k A[(r0+r)*PIT+k] * Wt[k*PIT + c0+c], k in [0,K)
template<int K>
__device__ __forceinline__ void mmTile4(const float* __restrict__ A,
                                        const float* __restrict__ Wt,
                                        float acc[4][4], int r0, int c0)
{
#pragma unroll 2
  for (int k0 = 0; k0 < K; k0 += 4) {
    float4 a4[4], w4[4];
#pragma unroll
    for (int r = 0; r < 4; ++r) a4[r] = ld4(A + (r0 + r) * PIT + k0);
#pragma unroll
    for (int kk = 0; kk < 4; ++kk) w4[kk] = ld4(Wt + (kk + k0) * PIT + c0);
#pragma unroll
    for (int r = 0; r < 4; ++r) {
      const float* ar = &a4[r].x;
#pragma unroll
      for (int c = 0; c < 4; ++c) {
        acc[r][c] += ar[0] * (&w4[0].x)[c] + ar[1] * (&w4[1].x)[c]
                   + ar[2] * (&w4[2].x)[c] + ar[3] * (&w4[3].x)[c];
      }
    }
  }
}

// O = act(A @ Wt * scale + bias); A:[64][PIT], Wt (transposed weight):[64][PIT]
template<int RELU, int TRANS>
__device__ __attribute__((noinline)) void mm64(const float* __restrict__ A,
                                               const float* __restrict__ Wt,
                                               float* __restrict__ O,
                                               const float* __restrict__ bias,
                                               float scale)
{
  const int ty = threadIdx.x >> 4, tx = threadIdx.x & 15;
  const int r0 = ty * 4, c0 = tx * 4;
  float acc[4][4] = {};
  mmTile4<64>(A, Wt, acc, r0, c0);
#pragma unroll
  for (int r = 0; r < 4; ++r)
#pragma unroll
    for (int c = 0; c < 4; ++c) {
      float v = acc[r][c] * scale;
      if (bias) v += bias[c0 + c];
      if (RELU) v = fmaxf(v, 0.f);
      if (TRANS) O[(c0 + c) * PIT + (r0 + r)] = v;
      else       O[(r0 + r) * PIT + (c0 + c)] = v;
    }
}

__device__ __forceinline__ void st44(float* __restrict__ O, const float acc[4][4],
                                     int r0, int c0)
{
#pragma unroll
  for (int r = 0; r < 4; ++r)
#pragma unroll
    for (int c = 0; c < 4; ++c)
      O[(r0 + r) * PIT + (c0 + c)] = acc[r][c];
}

// O[68][PIT] = A[68][PIT] @ Wt[64][PIT]   (no bias/act)
__device__ __attribute__((noinline)) void mm68(const float* __restrict__ A,
                                               const float* __restrict__ Wt,
                                               float* __restrict__ O)
{
  const int ty = threadIdx.x >> 4, tx = threadIdx.x & 15;
  {
    float acc[4][4] = {};
    mmTile4<64>(A, Wt, acc, ty * 4, tx * 4);
    st44(O, acc, ty * 4, tx * 4);
  }
  if (threadIdx.x < 16) {
    float acc[4][4] = {};
    mmTile4<64>(A, Wt, acc, 64, threadIdx.x * 4);
    st44(O, acc, 64, threadIdx.x * 4);
  }
}

// stage 64x64 row-major weight W[j][k] transposed into dst[k*PIT + j]
__device__ __forceinline__ void stageWT(const float* __restrict__ W,
                                        float* __restrict__ dst)
{
  for (int i = threadIdx.x; i < 64 * 64; i += TPB) {
    int j = i >> 6, k = i & 63;
    dst[k * PIT + j] = W[i];
  }
}

// row-wise softmax over cols 0..63 of S[64][PIT]; 4 threads per row
__device__ __forceinline__ void softmax64(float* __restrict__ S)
{
  int row = threadIdx.x >> 2, q = threadIdx.x & 3;
  float* r = S + row * PIT + q * 16;
  float v[16];
  float m = -1e30f;
#pragma unroll
  for (int j = 0; j < 16; ++j) { v[j] = r[j]; m = fmaxf(m, v[j]); }
  m = fmaxf(m, __shfl_xor(m, 1));
  m = fmaxf(m, __shfl_xor(m, 2));
  float ssum = 0.f;
#pragma unroll
  for (int j = 0; j < 16; ++j) { v[j] = __expf(v[j] - m); ssum += v[j]; }
  ssum += __shfl_xor(ssum, 1);
  ssum += __shfl_xor(ssum, 2);
  float inv = 1.f / ssum;
#pragma unroll
  for (int j = 0; j < 16; ++j) r[j] = v[j] * inv;
}

// Y = LayerNorm(Y + Aadd) * g + be, rows of 64; 4 threads per row
__device__ __forceinline__ void ln64(float* __restrict__ Y,
                                     const float* __restrict__ Aadd,
                                     const float* __restrict__ g,
                                     const float* __restrict__ be)
{
  int row = threadIdx.x >> 2, q = threadIdx.x & 3;
  float* yr = Y + row * PIT + q * 16;
  const float* ar = Aadd + row * PIT + q * 16;
  float v[16];
  float s1 = 0.f;
#pragma unroll
  for (int j = 0; j < 16; ++j) { v[j] = yr[j] + ar[j]; s1 += v[j]; }
  s1 += __shfl_xor(s1, 1);
  s1 += __shfl_xor(s1, 2);
  float mu = s1 * (1.f / 64.f);
  float s2 = 0.f;
#pragma unroll
  for (int j = 0; j < 16; ++j) { float t = v[j] - mu; s2 += t * t; }
  s2 += __shfl_xor(s2, 1);
  s2 += __shfl_xor(s2, 2);
  float rstd = rsqrtf(s2 * (1.f / 64.f) + 1e-5f);
#pragma unroll
  for (int j = 0; j < 16; ++j)
    yr[j] = (v[j] - mu) * rstd * g[q * 16 + j] + be[q * 16 + j];
}

__global__ __launch_bounds__(TPB)
void gcrnn_kernel(const float* __restrict__ x,      // (128,3,64,96)
                  const float* __restrict__ adj,    // (64,64)
                  const float* __restrict__ h0,     // (128,64,64)
                  const float* __restrict__ t_inw,  // (2,192,64)
                  const float* __restrict__ t_inb,  // (2,192)
                  const float* __restrict__ t_ow,   // (2,64,64)
                  const float* __restrict__ t_ob,   // (2,64)
                  const float* __restrict__ t_w1,   // (2,64,64)
                  const float* __restrict__ t_b1,   // (2,64)
                  const float* __restrict__ t_w2,   // (2,64,64)
                  const float* __restrict__ t_b2,   // (2,64)
                  const float* __restrict__ t_g1,   // (2,64)
                  const float* __restrict__ t_be1,  // (2,64)
                  const float* __restrict__ t_g2,   // (2,64)
                  const float* __restrict__ t_be2,  // (2,64)
                  const float* __restrict__ uw,     // (64,204)
                  const float* __restrict__ ub,     // (64)
                  const float* __restrict__ cw,     // (64,204)
                  const float* __restrict__ cb,     // (64)
                  float* __restrict__ out)          // (128,64,64,96) = (b,n,d,s)
{
  const int b = blockIdx.x;
  const int tid = threadIdx.x;
  const int ty = tid >> 4, tx = tid & 15;

  __shared__ float adjT[64 * PIT];        // adjT[v][w] = adj[w][v]
  __shared__ float hs[64 * PIT];          // h[dd][n]
  __shared__ float ys[64 * PIT];          // y[n][dd] (encoder activations)
  __shared__ float wsA[64 * PIT];         // staged transposed weight
  __shared__ float pool[4 * 64 * PIT];    // q/k/v/s   OR   xg/x1/x2

  float* bufQ = pool;
  float* bufK = pool + 64 * PIT;
  float* bufV = pool + 2 * 64 * PIT;
  float* bufS = pool + 3 * 64 * PIT;
  float* xg  = pool;                 // 68 rows
  float* x1b = pool + 68 * PIT;      // 68 rows
  float* x2b = pool + 2 * 68 * PIT;  // 68 rows (ends at 13872 < 17408)

  // adj transposed into LDS (persists across steps)
  for (int i = tid; i < 64 * 64; i += TPB) {
    int w = i >> 6, v = i & 63;            // read coalesced over v
    adjT[v * PIT + w] = adj[i];
  }
  // h init
  for (int i = tid; i < 64 * 64; i += TPB) {
    int dd = i >> 6, n = i & 63;
    hs[dd * PIT + n] = h0[(size_t)b * 4096 + i];
  }
  __syncthreads();

  const float* times = x + ((size_t)b * 3 + 2) * 64 * 96;  // x[b,2,0,:]

  for (int s = 0; s < 96; ++s) {
    float d = (s == 0) ? 0.f : (times[s] - times[s - 1]);
    float sq1 = sqrtf(1.f - d), sq2 = sqrtf(d);

    // y = h^T
    for (int i = tid; i < 64 * 64; i += TPB) {
      int n = i >> 6, dd = i & 63;
      ys[n * PIT + dd] = hs[dd * PIT + n];
    }
    __syncthreads();

    // ---- two encoder layers ----
    for (int l = 0; l < 2; ++l) {
      const float* inw = t_inw + l * 192 * 64;
      const float* inb = t_inb + l * 192;
      const float* ow  = t_ow  + l * 4096;
      const float* ob  = t_ob  + l * 64;
      const float* w1  = t_w1  + l * 4096;
      const float* b1  = t_b1  + l * 64;
      const float* w2  = t_w2  + l * 4096;
      const float* b2  = t_b2  + l * 64;
      const float* g1  = t_g1  + l * 64;
      const float* be1 = t_be1 + l * 64;
      const float* g2  = t_g2  + l * 64;
      const float* be2 = t_be2 + l * 64;

      stageWT(inw, wsA);                              __syncthreads();
      mm64<0, 0>(ys, wsA, bufQ, inb, 1.f);            __syncthreads();
      stageWT(inw + 4096, wsA);                       __syncthreads();
      mm64<0, 1>(ys, wsA, bufK, inb + 64, 1.f);       __syncthreads();  // K^T
      stageWT(inw + 8192, wsA);                       __syncthreads();
      mm64<0, 0>(ys, wsA, bufV, inb + 128, 1.f);      __syncthreads();
      mm64<0, 0>(bufQ, bufK, bufS, nullptr, 0.125f);  __syncthreads();  // QK^T/8
      softmax64(bufS);                                __syncthreads();
      mm64<0, 0>(bufS, bufV, bufQ, nullptr, 1.f);     __syncthreads();  // P@V
      stageWT(ow, wsA);                               __syncthreads();
      mm64<0, 0>(bufQ, wsA, bufK, ob, 1.f);           __syncthreads();  // proj
      ln64(ys, bufK, g1, be1);                        __syncthreads();
      stageWT(w1, wsA);                               __syncthreads();
      mm64<1, 0>(ys, wsA, bufQ, b1, 1.f);             __syncthreads();  // relu FF1
      stageWT(w2, wsA);                               __syncthreads();
      mm64<0, 0>(bufQ, wsA, bufK, b2, 1.f);           __syncthreads();  // FF2
      ln64(ys, bufK, g2, be2);                        __syncthreads();
    }

    // ---- xg = [xt(3); d(1); hd(64)], hd = sq1*h - sq2*eps, eps = y^T ----
    for (int i = tid; i < 3 * 64; i += TPB) {
      int f = i >> 6, n = i & 63;
      xg[f * PIT + n] = x[(((size_t)b * 3 + f) * 64 + n) * 96 + s];
    }
    if (tid < 64) xg[3 * PIT + tid] = d;
    for (int i = tid; i < 64 * 64; i += TPB) {
      int dd = i >> 6, n = i & 63;
      xg[(4 + dd) * PIT + n] = sq1 * hs[dd * PIT + n] - sq2 * ys[n * PIT + dd];
    }
    __syncthreads();

    // ---- diffusion: x1 = xg @ adj^T, x2 = x1 @ adj^T ----
    mm68(xg, adjT, x1b);  __syncthreads();
    mm68(x1b, adjT, x2b); __syncthreads();

    // ---- conv: u/c over z = [xg; x1; x2] (204 channels), fused ----
    float accU[4][4] = {}, accC[4][4] = {};
    for (int chunk = 0; chunk < 3; ++chunk) {
      __syncthreads();  // protect wsA / ys restage
      const float* wu = uw + chunk * 68;
      const float* wc = cw + chunk * 68;
      for (int i = tid; i < 64 * 68; i += TPB) {
        int o = i / 68, cc = i - o * 68;
        wsA[o * PIT + cc] = wu[(size_t)o * 204 + cc];
        ys[o * PIT + cc]  = wc[(size_t)o * 204 + cc];
      }
      __syncthreads();
      const float* Z = (chunk == 0) ? xg : ((chunk == 1) ? x1b : x2b);
      const int r0 = ty * 4, c0 = tx * 4;
#pragma unroll 2
      for (int k0 = 0; k0 < 68; k0 += 4) {
        float4 au[4], ac[4], wz[4];
#pragma unroll
        for (int r = 0; r < 4; ++r) {
          au[r] = ld4(wsA + (r0 + r) * PIT + k0);
          ac[r] = ld4(ys  + (r0 + r) * PIT + k0);
        }
#pragma unroll
        for (int kk = 0; kk < 4; ++kk) wz[kk] = ld4(Z + (k0 + kk) * PIT + c0);
#pragma unroll
        for (int r = 0; r < 4; ++r) {
          const float* pu = &au[r].x;
          const float* pc = &ac[r].x;
#pragma unroll
          for (int c = 0; c < 4; ++c) {
            float zc0 = (&wz[0].x)[c], zc1 = (&wz[1].x)[c],
                  zc2 = (&wz[2].x)[c], zc3 = (&wz[3].x)[c];
            accU[r][c] += pu[0] * zc0 + pu[1] * zc1 + pu[2] * zc2 + pu[3] * zc3;
            accC[r][c] += pc[0] * zc0 + pc[1] * zc1 + pc[2] * zc2 + pc[3] * zc3;
          }
        }
      }
    }
    __syncthreads();

    // ---- gate + update h, write output out[b,n,o,s] ----
    {
      const int r0 = ty * 4, c0 = tx * 4;
#pragma unroll
      for (int r = 0; r < 4; ++r) {
        int o = r0 + r;
        float bu = ub[o], bc = cb[o];
#pragma unroll
        for (int c = 0; c < 4; ++c) {
          int n = c0 + c;
          float uval = 1.f / (1.f + __expf(-(accU[r][c] + bu)));
          float cval = tanhf(accC[r][c] + bc);
          float hd = xg[(4 + o) * PIT + n];
          float hn = uval * hd + (1.f - uval) * cval;
          hs[o * PIT + n] = hn;
          out[(((size_t)b * 64 + n) * 64 + o) * 96 + s] = hn;
        }
      }
    }
    __syncthreads();
  }
}

extern "C" void kernel_launch(void* const* d_in, const int* in_sizes, int n_in,
                              void* d_out, int out_size, void* d_ws, size_t ws_size,
                              hipStream_t stream)
{
  (void)in_sizes; (void)n_in; (void)out_size; (void)d_ws; (void)ws_size;
  const float* x     = (const float*)d_in[0];
  const float* adj   = (const float*)d_in[1];
  // d_in[2] = lengths (unused by the reference)
  const float* h0    = (const float*)d_in[3];
  const float* t_inw = (const float*)d_in[4];
  const float* t_inb = (const float*)d_in[5];
  const float* t_ow  = (const float*)d_in[6];
  const float* t_ob  = (const float*)d_in[7];
  const float* t_w1  = (const float*)d_in[8];
  const float* t_b1  = (const float*)d_in[9];
  const float* t_w2  = (const float*)d_in[10];
  const float* t_b2  = (const float*)d_in[11];
  const float* t_g1  = (const float*)d_in[12];
  const float* t_be1 = (const float*)d_in[13];
  const float* t_g2  = (const float*)d_in[14];
  const float* t_be2 = (const float*)d_in[15];
  const float* uw    = (const float*)d_in[16];
  const float* ub    = (const float*)d_in[17];
  const float* cw    = (const float*)d_in[18];
  const float* cb    = (const float*)d_in[19];
  float* out = (float*)d_out;

  hipLaunchKernelGGL(gcrnn_kernel, dim3(128), dim3(TPB), 0, stream,
                     x, adj, h0, t_inw, t_inb, t_ow, t_ob, t_w1, t_b1,
                     t_w2, t_b2, t_g1, t_be1, t_g2, t_be2, uw, ub, cw, cb, out);
}

// Round 2
// 5344.868 us; speedup vs baseline: 2.6125x; 2.6125x over previous
//
#include <hip/hip_runtime.h>
#include <math.h>

#define TPB 256

typedef __attribute__((ext_vector_type(8))) short bf16x8;
typedef __attribute__((ext_vector_type(4))) float f32x4;
typedef unsigned short u16;

#define MFMA(a, b, c) __builtin_amdgcn_mfma_f32_16x16x32_bf16(a, b, c, 0, 0, 0)

__device__ __forceinline__ u16 f2bf(float f) {
  union { float f; unsigned u; } v; v.f = f;
  unsigned u = v.u;
  return (u16)((u + 0x7fffu + ((u >> 16) & 1u)) >> 16);  // RNE
}
__device__ __forceinline__ float bf2f(u16 h) {
  union { unsigned u; float f; } v; v.u = ((unsigned)h) << 16; return v.f;
}

// A/B fragment from LDS bf16 buffer laid out [row][pitch] (pitch in elements).
// lane holds row = row0 + (lane&15), k = kb + (lane>>4)*8 + j  (j=0..7)
__device__ __forceinline__ bf16x8 fragL(const u16* B, int row0, int pitch, int kb, int lane) {
  return *(const bf16x8*)(B + (row0 + (lane & 15)) * pitch + kb + ((lane >> 4) << 3));
}
// fragment from global fp32 [row][stride], converted to bf16
__device__ __forceinline__ bf16x8 fragG(const float* __restrict__ W, int row0, int stride,
                                        int kb, int lane) {
  const float* p = W + (size_t)(row0 + (lane & 15)) * stride + kb + ((lane >> 4) << 3);
  float4 a = *(const float4*)p, b = *(const float4*)(p + 4);
  bf16x8 r;
  r[0] = (short)f2bf(a.x); r[1] = (short)f2bf(a.y); r[2] = (short)f2bf(a.z); r[3] = (short)f2bf(a.w);
  r[4] = (short)f2bf(b.x); r[5] = (short)f2bf(b.y); r[6] = (short)f2bf(b.z); r[7] = (short)f2bf(b.w);
  return r;
}
// masked variant for K tails (k >= K reads as 0)
__device__ __forceinline__ bf16x8 fragGm(const float* __restrict__ W, int row0, int stride,
                                         int kb, int lane, int K) {
  const float* p = W + (size_t)(row0 + (lane & 15)) * stride;
  int k0 = kb + ((lane >> 4) << 3);
  bf16x8 r;
#pragma unroll
  for (int j = 0; j < 8; ++j) { int k = k0 + j; r[j] = (short)(k < K ? f2bf(p[k]) : (u16)0); }
  return r;
}

// residual + LayerNorm epilogue on a 16x64 stripe of acc frags; updates ysB in place.
__device__ __forceinline__ void lnEpilogue(f32x4 acc[4], const float* __restrict__ bias,
                                           const float* __restrict__ g, const float* __restrict__ be,
                                           u16* __restrict__ ysB, int m0, int lane) {
  float t[4][4];
#pragma unroll
  for (int f = 0; f < 4; ++f) {
    int col = f * 16 + (lane & 15);
    float bv = bias[col];
#pragma unroll
    for (int j = 0; j < 4; ++j) {
      int row = m0 + ((lane >> 4) << 2) + j;
      t[f][j] = acc[f][j] + bv + bf2f(ysB[row * 72 + col]);
    }
  }
#pragma unroll
  for (int j = 0; j < 4; ++j) {
    float s1 = t[0][j] + t[1][j] + t[2][j] + t[3][j];
    s1 += __shfl_xor(s1, 1); s1 += __shfl_xor(s1, 2);
    s1 += __shfl_xor(s1, 4); s1 += __shfl_xor(s1, 8);
    float mu = s1 * 0.015625f;
    float d0 = t[0][j] - mu, d1 = t[1][j] - mu, d2 = t[2][j] - mu, d3 = t[3][j] - mu;
    float s2 = d0 * d0 + d1 * d1 + d2 * d2 + d3 * d3;
    s2 += __shfl_xor(s2, 1); s2 += __shfl_xor(s2, 2);
    s2 += __shfl_xor(s2, 4); s2 += __shfl_xor(s2, 8);
    float rstd = rsqrtf(s2 * 0.015625f + 1e-5f);
#pragma unroll
    for (int f = 0; f < 4; ++f) {
      int col = f * 16 + (lane & 15);
      int row = m0 + ((lane >> 4) << 2) + j;
      ysB[row * 72 + col] = f2bf((t[f][j] - mu) * rstd * g[col] + be[col]);
    }
  }
}

__global__ __launch_bounds__(TPB, 1)
void gcrnn_kernel(const float* __restrict__ x,      // (128,3,64,96)
                  const float* __restrict__ adj,    // (64,64)
                  const float* __restrict__ h0,     // (128,64,64)
                  const float* __restrict__ t_inw, const float* __restrict__ t_inb,
                  const float* __restrict__ t_ow,  const float* __restrict__ t_ob,
                  const float* __restrict__ t_w1,  const float* __restrict__ t_b1,
                  const float* __restrict__ t_w2,  const float* __restrict__ t_b2,
                  const float* __restrict__ t_g1,  const float* __restrict__ t_be1,
                  const float* __restrict__ t_g2,  const float* __restrict__ t_be2,
                  const float* __restrict__ uw,    const float* __restrict__ ub,
                  const float* __restrict__ cw,    const float* __restrict__ cb,
                  float* __restrict__ wsOut,       // staging [b][s][d][n] (if useStage)
                  float* __restrict__ out,         // (128,64,64,96)
                  int useStage)
{
  const int b = blockIdx.x;
  const int tid = threadIdx.x;
  const int wv = tid >> 6;          // wave id 0..3
  const int lane = tid & 63;
  const int m0 = wv * 16;           // row stripe for 64-row matmuls

  __shared__ __align__(16) u16 adjB[64 * 72];    // adj[w][v] bf16
  __shared__ __align__(16) float hsF[64 * 68];   // h state fp32 [d][n]
  __shared__ __align__(16) u16 ysB[64 * 72];     // encoder activation [n][d]
  __shared__ __align__(16) u16 Qb[64 * 72];
  __shared__ __align__(16) u16 Kb[64 * 72];
  __shared__ __align__(16) u16 VTb[64 * 72];     // V^T [d][n]
  __shared__ __align__(16) u16 Pb[64 * 72];      // softmax probs [n][m]
  __shared__ __align__(16) u16 xgB[80 * 72];     // xg [c][v], rows 68..79 zero
  __shared__ __align__(16) u16 x1B[80 * 72];     // x1 [c][w]
  __shared__ __align__(16) u16 zTB[64 * 232];    // zT [n][c: 0..67 xgT | 68..135 x1T | 136..203 x2T | pad 0]

  // ---- one-time init ----
  for (int i = tid; i < 64 * 64; i += TPB) {
    adjB[(i >> 6) * 72 + (i & 63)] = f2bf(adj[i]);
    hsF[(i >> 6) * 68 + (i & 63)] = h0[(size_t)b * 4096 + i];
  }
  for (int i = tid; i < 12 * 64; i += TPB)        // xg pad rows 68..79
    xgB[(68 + (i >> 6)) * 72 + (i & 63)] = 0;
  for (int i = tid; i < 64 * 28; i += TPB)        // zT pad cols 204..231
    zTB[(i / 28) * 232 + 204 + (i % 28)] = 0;
  __syncthreads();

  const float* times = x + ((size_t)b * 3 + 2) * 64 * 96;  // x[b,2,0,:]

  for (int s = 0; s < 96; ++s) {
    float dcur = (s == 0) ? 0.f : (times[s] - times[s - 1]);
    float sq1 = sqrtf(1.f - dcur), sq2 = sqrtf(dcur);

    // ---- phase 0: ys = h^T (bf16) ----
    for (int i = tid; i < 64 * 64; i += TPB) {
      int n = i >> 6, dd = i & 63;
      ysB[n * 72 + dd] = f2bf(hsF[dd * 68 + n]);
    }
    __syncthreads();

    // ---- two encoder layers ----
    for (int l = 0; l < 2; ++l) {
      const float* inw = t_inw + l * 192 * 64;
      const float* inb = t_inb + l * 192;
      const float* ow  = t_ow  + l * 4096;
      const float* ob  = t_ob  + l * 64;
      const float* w1  = t_w1  + l * 4096;
      const float* bb1 = t_b1  + l * 64;
      const float* w2  = t_w2  + l * 4096;
      const float* bb2 = t_b2  + l * 64;
      const float* g1  = t_g1  + l * 64;
      const float* be1 = t_be1 + l * 64;
      const float* g2  = t_g2  + l * 64;
      const float* be2 = t_be2 + l * 64;

      // ---- A: Q, K, VT ----
      {
        bf16x8 ya0 = fragL(ysB, m0, 72, 0, lane);
        bf16x8 ya1 = fragL(ysB, m0, 72, 32, lane);
        for (int qk = 0; qk < 2; ++qk) {
          const float* W = inw + qk * 4096;
          const float* bias = inb + qk * 64;
          u16* dst = qk ? Kb : Qb;
#pragma unroll
          for (int f = 0; f < 4; ++f) {
            f32x4 acc = {0.f, 0.f, 0.f, 0.f};
            bf16x8 b0 = fragG(W, f * 16, 64, 0, lane);
            bf16x8 b1 = fragG(W, f * 16, 64, 32, lane);
            acc = MFMA(ya0, b0, acc); acc = MFMA(ya1, b1, acc);
            int col = f * 16 + (lane & 15);
            float bv = bias[col];
#pragma unroll
            for (int j = 0; j < 4; ++j) {
              int row = m0 + ((lane >> 4) << 2) + j;
              dst[row * 72 + col] = f2bf(acc[j] + bv);
            }
          }
        }
        {
          const float* Wv = inw + 2 * 4096;
          bf16x8 wa0 = fragG(Wv, m0, 64, 0, lane);
          bf16x8 wa1 = fragG(Wv, m0, 64, 32, lane);
#pragma unroll
          for (int f = 0; f < 4; ++f) {
            f32x4 acc = {0.f, 0.f, 0.f, 0.f};
            bf16x8 b0 = fragL(ysB, f * 16, 72, 0, lane);
            bf16x8 b1 = fragL(ysB, f * 16, 72, 32, lane);
            acc = MFMA(wa0, b0, acc); acc = MFMA(wa1, b1, acc);
            int col = f * 16 + (lane & 15);
#pragma unroll
            for (int j = 0; j < 4; ++j) {
              int row = m0 + ((lane >> 4) << 2) + j;
              VTb[row * 72 + col] = f2bf(acc[j] + inb[128 + row]);
            }
          }
        }
      }
      __syncthreads();

      // ---- B: scores + softmax -> P ----
      {
        bf16x8 qa0 = fragL(Qb, m0, 72, 0, lane);
        bf16x8 qa1 = fragL(Qb, m0, 72, 32, lane);
        f32x4 sc[4];
#pragma unroll
        for (int f = 0; f < 4; ++f) {
          f32x4 acc = {0.f, 0.f, 0.f, 0.f};
          bf16x8 b0 = fragL(Kb, f * 16, 72, 0, lane);
          bf16x8 b1 = fragL(Kb, f * 16, 72, 32, lane);
          acc = MFMA(qa0, b0, acc); acc = MFMA(qa1, b1, acc);
          sc[f] = acc;
        }
#pragma unroll
        for (int f = 0; f < 4; ++f)
#pragma unroll
          for (int j = 0; j < 4; ++j) sc[f][j] *= 0.125f;
        float inv[4];
#pragma unroll
        for (int j = 0; j < 4; ++j) {
          float m1 = fmaxf(fmaxf(sc[0][j], sc[1][j]), fmaxf(sc[2][j], sc[3][j]));
          m1 = fmaxf(m1, __shfl_xor(m1, 1)); m1 = fmaxf(m1, __shfl_xor(m1, 2));
          m1 = fmaxf(m1, __shfl_xor(m1, 4)); m1 = fmaxf(m1, __shfl_xor(m1, 8));
          float s1 = 0.f;
#pragma unroll
          for (int f = 0; f < 4; ++f) { float e = __expf(sc[f][j] - m1); sc[f][j] = e; s1 += e; }
          s1 += __shfl_xor(s1, 1); s1 += __shfl_xor(s1, 2);
          s1 += __shfl_xor(s1, 4); s1 += __shfl_xor(s1, 8);
          inv[j] = 1.f / s1;
        }
#pragma unroll
        for (int f = 0; f < 4; ++f) {
          int col = f * 16 + (lane & 15);
#pragma unroll
          for (int j = 0; j < 4; ++j) {
            int row = m0 + ((lane >> 4) << 2) + j;
            Pb[row * 72 + col] = f2bf(sc[f][j] * inv[j]);
          }
        }
      }
      __syncthreads();

      // ---- C: AO = P @ V  (-> Qb) ----
      {
        bf16x8 pa0 = fragL(Pb, m0, 72, 0, lane);
        bf16x8 pa1 = fragL(Pb, m0, 72, 32, lane);
#pragma unroll
        for (int f = 0; f < 4; ++f) {
          f32x4 acc = {0.f, 0.f, 0.f, 0.f};
          bf16x8 b0 = fragL(VTb, f * 16, 72, 0, lane);
          bf16x8 b1 = fragL(VTb, f * 16, 72, 32, lane);
          acc = MFMA(pa0, b0, acc); acc = MFMA(pa1, b1, acc);
          int col = f * 16 + (lane & 15);
#pragma unroll
          for (int j = 0; j < 4; ++j) {
            int row = m0 + ((lane >> 4) << 2) + j;
            Qb[row * 72 + col] = f2bf(acc[j]);
          }
        }
      }
      __syncthreads();

      // ---- D: proj + residual + LN -> ys ----
      {
        bf16x8 a0 = fragL(Qb, m0, 72, 0, lane);
        bf16x8 a1 = fragL(Qb, m0, 72, 32, lane);
        f32x4 acc[4];
#pragma unroll
        for (int f = 0; f < 4; ++f) {
          acc[f] = (f32x4){0.f, 0.f, 0.f, 0.f};
          bf16x8 b0 = fragG(ow, f * 16, 64, 0, lane);
          bf16x8 b1 = fragG(ow, f * 16, 64, 32, lane);
          acc[f] = MFMA(a0, b0, acc[f]); acc[f] = MFMA(a1, b1, acc[f]);
        }
        lnEpilogue(acc, ob, g1, be1, ysB, m0, lane);
      }
      __syncthreads();

      // ---- E: FF1 = relu(ys @ w1^T + b1)  (-> Kb) ----
      {
        bf16x8 a0 = fragL(ysB, m0, 72, 0, lane);
        bf16x8 a1 = fragL(ysB, m0, 72, 32, lane);
#pragma unroll
        for (int f = 0; f < 4; ++f) {
          f32x4 acc = {0.f, 0.f, 0.f, 0.f};
          bf16x8 b0 = fragG(w1, f * 16, 64, 0, lane);
          bf16x8 b1 = fragG(w1, f * 16, 64, 32, lane);
          acc = MFMA(a0, b0, acc); acc = MFMA(a1, b1, acc);
          int col = f * 16 + (lane & 15);
          float bv = bb1[col];
#pragma unroll
          for (int j = 0; j < 4; ++j) {
            int row = m0 + ((lane >> 4) << 2) + j;
            Kb[row * 72 + col] = f2bf(fmaxf(acc[j] + bv, 0.f));
          }
        }
      }
      __syncthreads();

      // ---- F: FF2 + residual + LN -> ys ----
      {
        bf16x8 a0 = fragL(Kb, m0, 72, 0, lane);
        bf16x8 a1 = fragL(Kb, m0, 72, 32, lane);
        f32x4 acc[4];
#pragma unroll
        for (int f = 0; f < 4; ++f) {
          acc[f] = (f32x4){0.f, 0.f, 0.f, 0.f};
          bf16x8 b0 = fragG(w2, f * 16, 64, 0, lane);
          bf16x8 b1 = fragG(w2, f * 16, 64, 32, lane);
          acc[f] = MFMA(a0, b0, acc[f]); acc[f] = MFMA(a1, b1, acc[f]);
        }
        lnEpilogue(acc, bb2, g2, be2, ysB, m0, lane);
      }
      __syncthreads();
    }

    // ---- G: xg [c][v] and zT block0 [n][c] ----
    {
      for (int i = tid; i < 3 * 64; i += TPB) {
        int f = i >> 6, n = i & 63;
        xgB[f * 72 + n] = f2bf(x[(((size_t)b * 3 + f) * 64 + n) * 96 + s]);
      }
      if (tid < 64) xgB[3 * 72 + tid] = f2bf(dcur);
      for (int i = tid; i < 64 * 64; i += TPB) {
        int dd = i >> 6, n = i & 63;
        float hd = sq1 * hsF[dd * 68 + n] - sq2 * bf2f(ysB[n * 72 + dd]);
        xgB[(4 + dd) * 72 + n] = f2bf(hd);
      }
      for (int i = tid; i < 64 * 68; i += TPB) {
        int n = i / 68, c = i - n * 68;
        float v;
        if (c < 3)       v = x[(((size_t)b * 3 + c) * 64 + n) * 96 + s];
        else if (c == 3) v = dcur;
        else             v = sq1 * hsF[(c - 4) * 68 + n] - sq2 * bf2f(ysB[n * 72 + (c - 4)]);
        zTB[n * 232 + c] = f2bf(v);
      }
    }
    __syncthreads();

    // ---- H: x1 = xg·adjT  and  x1T -> zT[68..135] ----
    {
      for (int st = wv; st < 5; st += 4) {
        int mm = st * 16;
        bf16x8 a0 = fragL(xgB, mm, 72, 0, lane);
        bf16x8 a1 = fragL(xgB, mm, 72, 32, lane);
#pragma unroll
        for (int f = 0; f < 4; ++f) {
          f32x4 acc = {0.f, 0.f, 0.f, 0.f};
          bf16x8 b0 = fragL(adjB, f * 16, 72, 0, lane);
          bf16x8 b1 = fragL(adjB, f * 16, 72, 32, lane);
          acc = MFMA(a0, b0, acc); acc = MFMA(a1, b1, acc);
          int col = f * 16 + (lane & 15);
#pragma unroll
          for (int j = 0; j < 4; ++j) {
            int row = mm + ((lane >> 4) << 2) + j;
            x1B[row * 72 + col] = f2bf(acc[j]);
          }
        }
      }
      {
        bf16x8 a0 = fragL(adjB, m0, 72, 0, lane);
        bf16x8 a1 = fragL(adjB, m0, 72, 32, lane);
#pragma unroll
        for (int cf = 0; cf < 5; ++cf) {
          f32x4 acc = {0.f, 0.f, 0.f, 0.f};
          bf16x8 b0 = fragL(xgB, cf * 16, 72, 0, lane);
          bf16x8 b1 = fragL(xgB, cf * 16, 72, 32, lane);
          acc = MFMA(a0, b0, acc); acc = MFMA(a1, b1, acc);
          int c = cf * 16 + (lane & 15);
          if (c < 68) {
#pragma unroll
            for (int j = 0; j < 4; ++j) {
              int row = m0 + ((lane >> 4) << 2) + j;
              zTB[row * 232 + 68 + c] = f2bf(acc[j]);
            }
          }
        }
      }
    }
    __syncthreads();

    // ---- I: x2T -> zT[136..203] ----
    {
      bf16x8 a0 = fragL(adjB, m0, 72, 0, lane);
      bf16x8 a1 = fragL(adjB, m0, 72, 32, lane);
#pragma unroll
      for (int cf = 0; cf < 5; ++cf) {
        f32x4 acc = {0.f, 0.f, 0.f, 0.f};
        bf16x8 b0 = fragL(x1B, cf * 16, 72, 0, lane);
        bf16x8 b1 = fragL(x1B, cf * 16, 72, 32, lane);
        acc = MFMA(a0, b0, acc); acc = MFMA(a1, b1, acc);
        int c = cf * 16 + (lane & 15);
        if (c < 68) {
#pragma unroll
          for (int j = 0; j < 4; ++j) {
            int row = m0 + ((lane >> 4) << 2) + j;
            zTB[row * 232 + 136 + c] = f2bf(acc[j]);
          }
        }
      }
    }
    __syncthreads();

    // ---- J: conv (u,c) + gate -> hs ----
    {
      f32x4 aU[4], aC[4];
#pragma unroll
      for (int f = 0; f < 4; ++f) { aU[f] = (f32x4){0,0,0,0}; aC[f] = (f32x4){0,0,0,0}; }
      for (int ks = 0; ks < 7; ++ks) {
        int kb = ks * 32;
        bf16x8 a = fragL(zTB, m0, 232, kb, lane);
#pragma unroll
        for (int f = 0; f < 4; ++f) {
          bf16x8 bu, bc;
          if (ks < 6) {
            bu = fragG(uw, f * 16, 204, kb, lane);
            bc = fragG(cw, f * 16, 204, kb, lane);
          } else {
            bu = fragGm(uw, f * 16, 204, kb, lane, 204);
            bc = fragGm(cw, f * 16, 204, kb, lane, 204);
          }
          aU[f] = MFMA(a, bu, aU[f]); aC[f] = MFMA(a, bc, aC[f]);
        }
      }
#pragma unroll
      for (int f = 0; f < 4; ++f) {
        int o = f * 16 + (lane & 15);
        float bu_ = ub[o], bc_ = cb[o];
#pragma unroll
        for (int j = 0; j < 4; ++j) {
          int n = m0 + ((lane >> 4) << 2) + j;
          float uval = 1.f / (1.f + __expf(-(aU[f][j] + bu_)));
          float cval = tanhf(aC[f][j] + bc_);
          float hd = sq1 * hsF[o * 68 + n] - sq2 * bf2f(ysB[n * 72 + o]);
          float hn = uval * hd + (1.f - uval) * cval;
          hsF[o * 68 + n] = hn;
        }
      }
    }
    __syncthreads();

    // ---- K: emit h ----
    if (useStage) {
      float* dst = wsOut + ((size_t)b * 96 + s) * 4096;
      for (int i = tid; i < 4096; i += TPB) dst[i] = hsF[(i >> 6) * 68 + (i & 63)];
    } else {
      for (int i = tid; i < 4096; i += TPB) {
        int o = i >> 6, n = i & 63;
        out[((size_t)(b * 64 + n) * 64 + o) * 96 + s] = hsF[o * 68 + n];
      }
    }
    __syncthreads();
  }
}

// ws [b][s][d][n] -> out [b][n][d][s]
__global__ __launch_bounds__(256)
void transp_kernel(const float* __restrict__ ws, float* __restrict__ out) {
  int blk = blockIdx.x;
  int b = blk >> 6, o = blk & 63;
  __shared__ float t[96 * 68];
  for (int i = threadIdx.x; i < 96 * 64; i += 256) {
    int ss = i >> 6, n = i & 63;
    t[ss * 68 + n] = ws[((size_t)b * 96 + ss) * 4096 + o * 64 + n];
  }
  __syncthreads();
  for (int i = threadIdx.x; i < 64 * 96; i += 256) {
    int n = i / 96, ss = i - n * 96;
    out[((size_t)(b * 64 + n) * 64 + o) * 96 + ss] = t[ss * 68 + n];
  }
}

extern "C" void kernel_launch(void* const* d_in, const int* in_sizes, int n_in,
                              void* d_out, int out_size, void* d_ws, size_t ws_size,
                              hipStream_t stream)
{
  (void)in_sizes; (void)n_in; (void)out_size;
  const float* x     = (const float*)d_in[0];
  const float* adj   = (const float*)d_in[1];
  const float* h0    = (const float*)d_in[3];
  const float* t_inw = (const float*)d_in[4];
  const float* t_inb = (const float*)d_in[5];
  const float* t_ow  = (const float*)d_in[6];
  const float* t_ob  = (const float*)d_in[7];
  const float* t_w1  = (const float*)d_in[8];
  const float* t_b1  = (const float*)d_in[9];
  const float* t_w2  = (const float*)d_in[10];
  const float* t_b2  = (const float*)d_in[11];
  const float* t_g1  = (const float*)d_in[12];
  const float* t_be1 = (const float*)d_in[13];
  const float* t_g2  = (const float*)d_in[14];
  const float* t_be2 = (const float*)d_in[15];
  const float* uw    = (const float*)d_in[16];
  const float* ub    = (const float*)d_in[17];
  const float* cw    = (const float*)d_in[18];
  const float* cb    = (const float*)d_in[19];
  float* out = (float*)d_out;

  const size_t stageBytes = (size_t)128 * 96 * 4096 * 4;  // 201.3 MB
  int useStage = (ws_size >= stageBytes) ? 1 : 0;
  float* wsOut = (float*)d_ws;

  hipLaunchKernelGGL(gcrnn_kernel, dim3(128), dim3(TPB), 0, stream,
                     x, adj, h0, t_inw, t_inb, t_ow, t_ob, t_w1, t_b1,
                     t_w2, t_b2, t_g1, t_be1, t_g2, t_be2, uw, ub, cw, cb,
                     wsOut, out, useStage);
  if (useStage) {
    hipLaunchKernelGGL(transp_kernel, dim3(128 * 64), dim3(256), 0, stream, wsOut, out);
  }
}

// Round 3
// 1935.425 us; speedup vs baseline: 7.2146x; 2.7616x over previous
//
#include <hip/hip_runtime.h>
#include <math.h>

#define TPB 512

typedef __attribute__((ext_vector_type(8))) short bf16x8;
typedef __attribute__((ext_vector_type(4))) float f32x4;
typedef unsigned short u16;

#define MFMA(a, b, c) __builtin_amdgcn_mfma_f32_16x16x32_bf16(a, b, c, 0, 0, 0)

__device__ __forceinline__ u16 f2bf(float f) {
  union { float f; unsigned u; } v; v.f = f;
  unsigned u = v.u;
  return (u16)((u + 0x7fffu + ((u >> 16) & 1u)) >> 16);  // RNE
}
__device__ __forceinline__ float bf2f(u16 h) {
  union { unsigned u; float f; } v; v.u = ((unsigned)h) << 16; return v.f;
}

// fragment from LDS bf16 [row][pitch]: lane row = row0+(lane&15), k = kb+(lane>>4)*8+j
__device__ __forceinline__ bf16x8 fragL(const u16* B, int row0, int pitch, int kb, int lane) {
  return *(const bf16x8*)(B + (row0 + (lane & 15)) * pitch + kb + ((lane >> 4) << 3));
}
// fragment from global fp32 [row][stride] with on-the-fly bf16 convert (PREW=0 fallback)
__device__ __forceinline__ bf16x8 fragG(const float* __restrict__ W, int row0, int stride,
                                        int kb, int lane) {
  const float* p = W + (size_t)(row0 + (lane & 15)) * stride + kb + ((lane >> 4) << 3);
  float4 a = *(const float4*)p, b = *(const float4*)(p + 4);
  bf16x8 r;
  r[0] = (short)f2bf(a.x); r[1] = (short)f2bf(a.y); r[2] = (short)f2bf(a.z); r[3] = (short)f2bf(a.w);
  r[4] = (short)f2bf(b.x); r[5] = (short)f2bf(b.y); r[6] = (short)f2bf(b.z); r[7] = (short)f2bf(b.w);
  return r;
}

// encoder weight fragment: pre-swizzled bf16 in ws (PREW=1) or fp32 global (PREW=0)
template<int PREW>
__device__ __forceinline__ bf16x8 wfrag(const float* __restrict__ Wg,
                                        const u16* __restrict__ Wp,
                                        int m, int f, int kh, int lane) {
  if constexpr (PREW)
    return *(const bf16x8*)(Wp + (size_t)m * 4096 + f * 1024 + kh * 512 + lane * 8);
  else
    return fragG(Wg, f * 16, 64, kh * 32, lane);
}

// matmul(2 frags) + bias + residual + LayerNorm (cross-wave partials via red); updates ysB
template<int PREW>
__device__ __forceinline__ void mmLN(const u16* __restrict__ src,
                                     const float* __restrict__ Wg,
                                     const u16* __restrict__ Wp, int m,
                                     const float* __restrict__ bias,
                                     const float* __restrict__ g,
                                     const float* __restrict__ be,
                                     u16* __restrict__ ysB, float* __restrict__ red,
                                     int m0, int wc, int lane) {
  const int lx = lane & 15, wc2 = wc * 2;
  bf16x8 a0 = fragL(src, m0, 72, 0, lane);
  bf16x8 a1 = fragL(src, m0, 72, 32, lane);
  float t[2][4];
#pragma unroll
  for (int fl = 0; fl < 2; ++fl) {
    int f = wc2 + fl;
    f32x4 acc = {0.f, 0.f, 0.f, 0.f};
    acc = MFMA(a0, wfrag<PREW>(Wg, Wp, m, f, 0, lane), acc);
    acc = MFMA(a1, wfrag<PREW>(Wg, Wp, m, f, 1, lane), acc);
    int col = f * 16 + lx;
    float bv = bias[col];
#pragma unroll
    for (int j = 0; j < 4; ++j) {
      int row = m0 + ((lane >> 4) << 2) + j;
      t[fl][j] = acc[j] + bv + bf2f(ysB[row * 72 + col]);
    }
  }
  float s1v[4], s2v[4];
#pragma unroll
  for (int j = 0; j < 4; ++j) {
    float s1 = t[0][j] + t[1][j];
    float s2 = t[0][j] * t[0][j] + t[1][j] * t[1][j];
    s1 += __shfl_xor(s1, 1); s2 += __shfl_xor(s2, 1);
    s1 += __shfl_xor(s1, 2); s2 += __shfl_xor(s2, 2);
    s1 += __shfl_xor(s1, 4); s2 += __shfl_xor(s2, 4);
    s1 += __shfl_xor(s1, 8); s2 += __shfl_xor(s2, 8);
    s1v[j] = s1; s2v[j] = s2;
  }
  if (lx == 0) {
#pragma unroll
    for (int j = 0; j < 4; ++j) {
      int row = m0 + ((lane >> 4) << 2) + j;
      red[(wc * 64 + row) * 2 + 0] = s1v[j];
      red[(wc * 64 + row) * 2 + 1] = s2v[j];
    }
  }
  __syncthreads();
#pragma unroll
  for (int j = 0; j < 4; ++j) {
    int row = m0 + ((lane >> 4) << 2) + j;
    float mu = (red[row * 2 + 0] + red[(64 + row) * 2 + 0]) * 0.015625f;
    float m2 = (red[row * 2 + 1] + red[(64 + row) * 2 + 1]) * 0.015625f;
    float rstd = rsqrtf(m2 - mu * mu + 1e-5f);
#pragma unroll
    for (int fl = 0; fl < 2; ++fl) {
      int col = (wc2 + fl) * 16 + lx;
      ysB[row * 72 + col] = f2bf((t[fl][j] - mu) * rstd * g[col] + be[col]);
    }
  }
}

// pre-swizzle 12 encoder 64x64 matrices into bf16 fragment layout
__global__ __launch_bounds__(256)
void prep_kernel(const float* __restrict__ t_inw, const float* __restrict__ t_ow,
                 const float* __restrict__ t_w1, const float* __restrict__ t_w2,
                 u16* __restrict__ wp) {
  int m = blockIdx.x;            // 0..11 = layer*6 + {Wq,Wk,Wv,ow,w1,w2}
  int l = m / 6, r = m % 6;
  const float* W;
  if (r < 3)      W = t_inw + l * 12288 + r * 4096;
  else if (r == 3) W = t_ow + l * 4096;
  else if (r == 4) W = t_w1 + l * 4096;
  else             W = t_w2 + l * 4096;
  for (int t = threadIdx.x; t < 4096; t += 256) {
    int j = t & 7, ln = (t >> 3) & 63, kh = (t >> 9) & 1, f = t >> 10;
    int row = f * 16 + (ln & 15);
    int k = kh * 32 + ((ln >> 4) << 3) + j;
    wp[(size_t)m * 4096 + t] = f2bf(W[row * 64 + k]);
  }
}

template<int PREW>
__global__ __launch_bounds__(TPB, 1)
void gcrnn_kernel(const float* __restrict__ x,      // (128,3,64,96)
                  const float* __restrict__ adj,    // (64,64)
                  const float* __restrict__ h0,     // (128,64,64)
                  const float* __restrict__ t_inw, const float* __restrict__ t_inb,
                  const float* __restrict__ t_ow,  const float* __restrict__ t_ob,
                  const float* __restrict__ t_w1,  const float* __restrict__ t_b1,
                  const float* __restrict__ t_w2,  const float* __restrict__ t_b2,
                  const float* __restrict__ t_g1,  const float* __restrict__ t_be1,
                  const float* __restrict__ t_g2,  const float* __restrict__ t_be2,
                  const float* __restrict__ uw,    const float* __restrict__ ub,
                  const float* __restrict__ cw,    const float* __restrict__ cb,
                  const u16* __restrict__ wsW,     // pre-swizzled encoder weights (PREW)
                  float* __restrict__ wsOut,       // staging [b][s][d][n] (if useStage)
                  float* __restrict__ out,         // (128,64,64,96)
                  int useStage)
{
  const int b = blockIdx.x;
  const int tid = threadIdx.x;
  const int wv = tid >> 6;
  const int lane = tid & 63;
  const int lx = lane & 15;
  const int wr = wv & 3, wc = wv >> 2;
  const int wc2 = wc * 2;
  const int m0 = wr * 16;

  __shared__ __align__(16) u16 adjB[64 * 72];          // 9216 B  adj[w][v]
  __shared__ __align__(16) float hsF[64 * 65];          // 16640 B h[d][n] fp32 (pitch 65)
  __shared__ __align__(16) u16 ysB[64 * 72];            // 9216 B  y[n][d] / h^T
  __shared__ __align__(16) float red[2 * 64 * 2];       // 1024 B  cross-wave partials
  __shared__ __align__(16) u16 pool[18432];             // 36864 B Qb|Kb|VTb|Pb / xgB|x1B
  __shared__ __align__(16) u16 zTB[64 * 232];           // 29696 B zT[n][c], cols 204..231 = 0
  __shared__ __align__(16) u16 uwcwB[2 * 4 * 7 * 512];  // 57344 B conv weight frags
  // total 160000 B <= 163840

  u16* Qb  = pool;
  u16* Kb  = pool + 4608;
  u16* VTb = pool + 9216;
  u16* Pb  = pool + 13824;
  u16* xgB = pool;          // 80 rows x 72
  u16* x1B = pool + 5760;   // 80 rows x 72

  // ---- one-time init ----
  for (int i = tid; i < 4096; i += TPB) {
    int r = i >> 6, c = i & 63;
    float hv = h0[(size_t)b * 4096 + i];
    adjB[r * 72 + c] = f2bf(adj[i]);
    hsF[r * 65 + c] = hv;
    ysB[c * 72 + r] = f2bf(hv);
  }
  for (int i = tid; i < 2 * 4 * 7 * 512; i += TPB) {
    int t = i;
    int j = t & 7; t >>= 3;
    int ln = t & 63; t >>= 6;
    int kh = t % 7; t /= 7;
    int f = t & 3; int mat = t >> 2;
    int o = f * 16 + (ln & 15);
    int k = kh * 32 + ((ln >> 4) << 3) + j;
    const float* W = mat ? cw : uw;
    uwcwB[i] = (k < 204) ? f2bf(W[o * 204 + k]) : (u16)0;
  }
  for (int i = tid; i < 64 * 28; i += TPB)
    zTB[(i / 28) * 232 + 204 + (i % 28)] = 0;
  __syncthreads();

  const float* times = x + ((size_t)b * 3 + 2) * 64 * 96;  // x[b,2,0,:]

  for (int s = 0; s < 96; ++s) {
    float dcur = (s == 0) ? 0.f : (times[s] - times[s - 1]);
    float sq1 = sqrtf(1.f - dcur), sq2 = sqrtf(dcur);

    // ---- two encoder layers ----
    for (int l = 0; l < 2; ++l) {
      const int l6 = l * 6;
      const float* inw = t_inw + l * 12288;
      const float* inb = t_inb + l * 192;
      const float* ow  = t_ow  + l * 4096;
      const float* ob  = t_ob  + l * 64;
      const float* w1  = t_w1  + l * 4096;
      const float* bb1 = t_b1  + l * 64;
      const float* w2  = t_w2  + l * 4096;
      const float* bb2 = t_b2  + l * 64;
      const float* g1  = t_g1  + l * 64;
      const float* be1 = t_be1 + l * 64;
      const float* g2  = t_g2  + l * 64;
      const float* be2 = t_be2 + l * 64;

      // A: Q, K, V^T
      {
        bf16x8 ya0 = fragL(ysB, m0, 72, 0, lane);
        bf16x8 ya1 = fragL(ysB, m0, 72, 32, lane);
        for (int qk = 0; qk < 2; ++qk) {
          u16* dst = qk ? Kb : Qb;
          const float* bias = inb + qk * 64;
          const float* Wg = inw + qk * 4096;
#pragma unroll
          for (int fl = 0; fl < 2; ++fl) {
            int f = wc2 + fl;
            f32x4 acc = {0.f, 0.f, 0.f, 0.f};
            acc = MFMA(ya0, wfrag<PREW>(Wg, wsW, l6 + qk, f, 0, lane), acc);
            acc = MFMA(ya1, wfrag<PREW>(Wg, wsW, l6 + qk, f, 1, lane), acc);
            int col = f * 16 + lx;
            float bv = bias[col];
#pragma unroll
            for (int j = 0; j < 4; ++j) {
              int row = m0 + ((lane >> 4) << 2) + j;
              dst[row * 72 + col] = f2bf(acc[j] + bv);
            }
          }
        }
        {
          const float* Wv = inw + 8192;
          bf16x8 wa0 = wfrag<PREW>(Wv, wsW, l6 + 2, wr, 0, lane);
          bf16x8 wa1 = wfrag<PREW>(Wv, wsW, l6 + 2, wr, 1, lane);
#pragma unroll
          for (int fl = 0; fl < 2; ++fl) {
            int cf = wc2 + fl;
            f32x4 acc = {0.f, 0.f, 0.f, 0.f};
            acc = MFMA(wa0, fragL(ysB, cf * 16, 72, 0, lane), acc);
            acc = MFMA(wa1, fragL(ysB, cf * 16, 72, 32, lane), acc);
            int col = cf * 16 + lx;
#pragma unroll
            for (int j = 0; j < 4; ++j) {
              int row = m0 + ((lane >> 4) << 2) + j;
              VTb[row * 72 + col] = f2bf(acc[j] + inb[128 + row]);
            }
          }
        }
      }
      __syncthreads();

      // B: scores + softmax (cross-wave max/sum exchange, one barrier)
      {
        bf16x8 qa0 = fragL(Qb, m0, 72, 0, lane);
        bf16x8 qa1 = fragL(Qb, m0, 72, 32, lane);
        f32x4 sc[2];
#pragma unroll
        for (int fl = 0; fl < 2; ++fl) {
          int f = wc2 + fl;
          f32x4 acc = {0.f, 0.f, 0.f, 0.f};
          acc = MFMA(qa0, fragL(Kb, f * 16, 72, 0, lane), acc);
          acc = MFMA(qa1, fragL(Kb, f * 16, 72, 32, lane), acc);
#pragma unroll
          for (int j = 0; j < 4; ++j) acc[j] *= 0.125f;
          sc[fl] = acc;
        }
        float mw[4];
#pragma unroll
        for (int j = 0; j < 4; ++j) {
          float m1 = fmaxf(sc[0][j], sc[1][j]);
          m1 = fmaxf(m1, __shfl_xor(m1, 1));
          m1 = fmaxf(m1, __shfl_xor(m1, 2));
          m1 = fmaxf(m1, __shfl_xor(m1, 4));
          m1 = fmaxf(m1, __shfl_xor(m1, 8));
          float e0 = __expf(sc[0][j] - m1), e1 = __expf(sc[1][j] - m1);
          sc[0][j] = e0; sc[1][j] = e1;
          float s1 = e0 + e1;
          s1 += __shfl_xor(s1, 1); s1 += __shfl_xor(s1, 2);
          s1 += __shfl_xor(s1, 4); s1 += __shfl_xor(s1, 8);
          mw[j] = m1;
          if (lx == 0) {
            int row = m0 + ((lane >> 4) << 2) + j;
            red[(wc * 64 + row) * 2 + 0] = m1;
            red[(wc * 64 + row) * 2 + 1] = s1;
          }
        }
        __syncthreads();
        float scl[4];
#pragma unroll
        for (int j = 0; j < 4; ++j) {
          int row = m0 + ((lane >> 4) << 2) + j;
          float m0r = red[row * 2 + 0], m1r = red[(64 + row) * 2 + 0];
          float s0r = red[row * 2 + 1], s1r = red[(64 + row) * 2 + 1];
          float mm = fmaxf(m0r, m1r);
          float ss = s0r * __expf(m0r - mm) + s1r * __expf(m1r - mm);
          scl[j] = __expf(mw[j] - mm) / ss;
        }
#pragma unroll
        for (int fl = 0; fl < 2; ++fl) {
          int col = (wc2 + fl) * 16 + lx;
#pragma unroll
          for (int j = 0; j < 4; ++j) {
            int row = m0 + ((lane >> 4) << 2) + j;
            Pb[row * 72 + col] = f2bf(sc[fl][j] * scl[j]);
          }
        }
      }
      __syncthreads();

      // C: AO = P @ V -> Qb
      {
        bf16x8 pa0 = fragL(Pb, m0, 72, 0, lane);
        bf16x8 pa1 = fragL(Pb, m0, 72, 32, lane);
#pragma unroll
        for (int fl = 0; fl < 2; ++fl) {
          int cf = wc2 + fl;
          f32x4 acc = {0.f, 0.f, 0.f, 0.f};
          acc = MFMA(pa0, fragL(VTb, cf * 16, 72, 0, lane), acc);
          acc = MFMA(pa1, fragL(VTb, cf * 16, 72, 32, lane), acc);
          int col = cf * 16 + lx;
#pragma unroll
          for (int j = 0; j < 4; ++j) {
            int row = m0 + ((lane >> 4) << 2) + j;
            Qb[row * 72 + col] = f2bf(acc[j]);
          }
        }
      }
      __syncthreads();

      // D: proj + residual + LN
      mmLN<PREW>(Qb, ow, wsW, l6 + 3, ob, g1, be1, ysB, red, m0, wc, lane);
      __syncthreads();

      // E: FF1 relu -> Kb
      {
        bf16x8 a0 = fragL(ysB, m0, 72, 0, lane);
        bf16x8 a1 = fragL(ysB, m0, 72, 32, lane);
#pragma unroll
        for (int fl = 0; fl < 2; ++fl) {
          int f = wc2 + fl;
          f32x4 acc = {0.f, 0.f, 0.f, 0.f};
          acc = MFMA(a0, wfrag<PREW>(w1, wsW, l6 + 4, f, 0, lane), acc);
          acc = MFMA(a1, wfrag<PREW>(w1, wsW, l6 + 4, f, 1, lane), acc);
          int col = f * 16 + lx;
          float bv = bb1[col];
#pragma unroll
          for (int j = 0; j < 4; ++j) {
            int row = m0 + ((lane >> 4) << 2) + j;
            Kb[row * 72 + col] = f2bf(fmaxf(acc[j] + bv, 0.f));
          }
        }
      }
      __syncthreads();

      // F: FF2 + residual + LN
      mmLN<PREW>(Kb, w2, wsW, l6 + 5, bb2, g2, be2, ysB, red, m0, wc, lane);
      __syncthreads();
    }

    // G: xg [c][v] rows 0..67 and zT cols 0..67
    {
      for (int i = tid; i < 256; i += TPB) {
        int f = i >> 6, n = i & 63;
        float v = (f < 3) ? x[(((size_t)b * 3 + f) * 64 + n) * 96 + s] : dcur;
        xgB[f * 72 + n] = f2bf(v);
        zTB[n * 232 + f] = f2bf(v);
      }
      for (int i = tid; i < 4096; i += TPB) {
        int dd = i >> 6, n = i & 63;
        float hd = sq1 * hsF[dd * 65 + n] - sq2 * bf2f(ysB[n * 72 + dd]);
        xgB[(4 + dd) * 72 + n] = f2bf(hd);
      }
      for (int i = tid; i < 4096; i += TPB) {
        int n = i >> 6, dd = i & 63;
        float hd = sq1 * hsF[dd * 65 + n] - sq2 * bf2f(ysB[n * 72 + dd]);
        zTB[n * 232 + 4 + dd] = f2bf(hd);
      }
    }
    __syncthreads();

    // H: x1 = xg @ adj^T  and  x1T -> zT[68..135]
    {
      for (int st = wr; st < 5; st += 4) {
        int mm = st * 16;
        bf16x8 a0 = fragL(xgB, mm, 72, 0, lane);
        bf16x8 a1 = fragL(xgB, mm, 72, 32, lane);
#pragma unroll
        for (int fl = 0; fl < 2; ++fl) {
          int f = wc2 + fl;
          f32x4 acc = {0.f, 0.f, 0.f, 0.f};
          acc = MFMA(a0, fragL(adjB, f * 16, 72, 0, lane), acc);
          acc = MFMA(a1, fragL(adjB, f * 16, 72, 32, lane), acc);
          int col = f * 16 + lx;
#pragma unroll
          for (int j = 0; j < 4; ++j)
            x1B[(mm + ((lane >> 4) << 2) + j) * 72 + col] = f2bf(acc[j]);
        }
      }
      {
        bf16x8 a0 = fragL(adjB, m0, 72, 0, lane);
        bf16x8 a1 = fragL(adjB, m0, 72, 32, lane);
        int cfb = wc ? 3 : 0, cfe = wc ? 5 : 3;
        for (int cf = cfb; cf < cfe; ++cf) {
          f32x4 acc = {0.f, 0.f, 0.f, 0.f};
          acc = MFMA(a0, fragL(xgB, cf * 16, 72, 0, lane), acc);
          acc = MFMA(a1, fragL(xgB, cf * 16, 72, 32, lane), acc);
          int c = cf * 16 + lx;
          if (c < 68) {
#pragma unroll
            for (int j = 0; j < 4; ++j) {
              int row = m0 + ((lane >> 4) << 2) + j;
              zTB[row * 232 + 68 + c] = f2bf(acc[j]);
            }
          }
        }
      }
    }
    __syncthreads();

    // I: x2T -> zT[136..203]
    {
      bf16x8 a0 = fragL(adjB, m0, 72, 0, lane);
      bf16x8 a1 = fragL(adjB, m0, 72, 32, lane);
      int cfb = wc ? 3 : 0, cfe = wc ? 5 : 3;
      for (int cf = cfb; cf < cfe; ++cf) {
        f32x4 acc = {0.f, 0.f, 0.f, 0.f};
        acc = MFMA(a0, fragL(x1B, cf * 16, 72, 0, lane), acc);
        acc = MFMA(a1, fragL(x1B, cf * 16, 72, 32, lane), acc);
        int c = cf * 16 + lx;
        if (c < 68) {
#pragma unroll
          for (int j = 0; j < 4; ++j) {
            int row = m0 + ((lane >> 4) << 2) + j;
            zTB[row * 232 + 136 + c] = f2bf(acc[j]);
          }
        }
      }
    }
    __syncthreads();

    // J: conv (u,c) + gate -> hsF, ysB = h^T
    {
      f32x4 aU[2], aC[2];
      aU[0] = aU[1] = aC[0] = aC[1] = (f32x4){0.f, 0.f, 0.f, 0.f};
      for (int kh = 0; kh < 7; ++kh) {
        bf16x8 a = fragL(zTB, m0, 232, kh * 32, lane);
#pragma unroll
        for (int fl = 0; fl < 2; ++fl) {
          int f = wc2 + fl;
          const u16* pu = uwcwB + ((size_t)(f * 7 + kh)) * 512 + lane * 8;
          const u16* pc = uwcwB + ((size_t)((4 + f) * 7 + kh)) * 512 + lane * 8;
          aU[fl] = MFMA(a, *(const bf16x8*)pu, aU[fl]);
          aC[fl] = MFMA(a, *(const bf16x8*)pc, aC[fl]);
        }
      }
#pragma unroll
      for (int fl = 0; fl < 2; ++fl) {
        int o = (wc2 + fl) * 16 + lx;
        float bu_ = ub[o], bc_ = cb[o];
#pragma unroll
        for (int j = 0; j < 4; ++j) {
          int n = m0 + ((lane >> 4) << 2) + j;
          float u = 1.f / (1.f + __expf(-(aU[fl][j] + bu_)));
          float z = aC[fl][j] + bc_;
          z = fminf(fmaxf(z, -15.f), 15.f);
          float e2 = __expf(2.f * z);
          float cval = (e2 - 1.f) / (e2 + 1.f);
          float hd = sq1 * hsF[o * 65 + n] - sq2 * bf2f(ysB[n * 72 + o]);
          float hn = u * hd + (1.f - u) * cval;
          hsF[o * 65 + n] = hn;
          ysB[n * 72 + o] = f2bf(hn);
        }
      }
    }
    __syncthreads();

    // K: emit h
    if (useStage) {
      float* dst = wsOut + ((size_t)b * 96 + s) * 4096;
      for (int i = tid; i < 4096; i += TPB) dst[i] = hsF[(i >> 6) * 65 + (i & 63)];
    } else {
      for (int i = tid; i < 4096; i += TPB) {
        int o = i >> 6, n = i & 63;
        out[((size_t)(b * 64 + n) * 64 + o) * 96 + s] = hsF[o * 65 + n];
      }
    }
    __syncthreads();
  }
}

// ws [b][s][d][n] -> out [b][n][d][s]
__global__ __launch_bounds__(256)
void transp_kernel(const float* __restrict__ ws, float* __restrict__ out) {
  int blk = blockIdx.x;
  int b = blk >> 6, o = blk & 63;
  __shared__ float t[96 * 68];
  for (int i = threadIdx.x; i < 96 * 64; i += 256) {
    int ss = i >> 6, n = i & 63;
    t[ss * 68 + n] = ws[((size_t)b * 96 + ss) * 4096 + o * 64 + n];
  }
  __syncthreads();
  for (int i = threadIdx.x; i < 64 * 96; i += 256) {
    int n = i / 96, ss = i - n * 96;
    out[((size_t)(b * 64 + n) * 64 + o) * 96 + ss] = t[ss * 68 + n];
  }
}

extern "C" void kernel_launch(void* const* d_in, const int* in_sizes, int n_in,
                              void* d_out, int out_size, void* d_ws, size_t ws_size,
                              hipStream_t stream)
{
  (void)in_sizes; (void)n_in; (void)out_size;
  const float* x     = (const float*)d_in[0];
  const float* adj   = (const float*)d_in[1];
  const float* h0    = (const float*)d_in[3];
  const float* t_inw = (const float*)d_in[4];
  const float* t_inb = (const float*)d_in[5];
  const float* t_ow  = (const float*)d_in[6];
  const float* t_ob  = (const float*)d_in[7];
  const float* t_w1  = (const float*)d_in[8];
  const float* t_b1  = (const float*)d_in[9];
  const float* t_w2  = (const float*)d_in[10];
  const float* t_b2  = (const float*)d_in[11];
  const float* t_g1  = (const float*)d_in[12];
  const float* t_be1 = (const float*)d_in[13];
  const float* t_g2  = (const float*)d_in[14];
  const float* t_be2 = (const float*)d_in[15];
  const float* uw    = (const float*)d_in[16];
  const float* ub    = (const float*)d_in[17];
  const float* cw    = (const float*)d_in[18];
  const float* cb    = (const float*)d_in[19];
  float* out = (float*)d_out;

  const size_t stageBytes = (size_t)128 * 96 * 4096 * 4;  // 201.3 MB
  const size_t wRegion = 131072;                          // 128 KB for weight frags
  int prew = 0, useStage = 0;
  size_t stageOff = 0;
  if (ws_size >= wRegion + stageBytes)      { prew = 1; useStage = 1; stageOff = wRegion; }
  else if (ws_size >= stageBytes)           { useStage = 1; }
  else if (ws_size >= wRegion)              { prew = 1; }

  u16* wsW = (u16*)d_ws;
  float* wsOut = (float*)((char*)d_ws + stageOff);

  if (prew)
    hipLaunchKernelGGL(prep_kernel, dim3(12), dim3(256), 0, stream,
                       t_inw, t_ow, t_w1, t_w2, wsW);

  if (prew)
    hipLaunchKernelGGL(gcrnn_kernel<1>, dim3(128), dim3(TPB), 0, stream,
                       x, adj, h0, t_inw, t_inb, t_ow, t_ob, t_w1, t_b1,
                       t_w2, t_b2, t_g1, t_be1, t_g2, t_be2, uw, ub, cw, cb,
                       wsW, wsOut, out, useStage);
  else
    hipLaunchKernelGGL(gcrnn_kernel<0>, dim3(128), dim3(TPB), 0, stream,
                       x, adj, h0, t_inw, t_inb, t_ow, t_ob, t_w1, t_b1,
                       t_w2, t_b2, t_g1, t_be1, t_g2, t_be2, uw, ub, cw, cb,
                       wsW, wsOut, out, useStage);

  if (useStage)
    hipLaunchKernelGGL(transp_kernel, dim3(128 * 64), dim3(256), 0, stream, wsOut, out);
}